// Round 5
// baseline (114.258 us; speedup 1.0000x reference)
//
#include <hip/hip_runtime.h>
#include <hip/hip_bf16.h>

// EGNN layer, MI355X. B=4, N=256, H=128, E=16, EIN=273. All I/O float32.
// h1 = pre_i(i) + pre_j(j) + d2*w_d2 + ef@Wef + be1 (layer-1 GEMM collapses to
// per-node precompute + 17x128 per-edge assembly); layer-2 128x128 GEMM via
// mfma_f32_16x16x32_bf16 with SWAPPED operands (D = We2^T x H1^T = EM^T) so
// each lane holds 4 consecutive output channels of one edge row ->
// global_store_dwordx4 (4x fewer store instrs). k_edge: 512 threads / 8 waves,
// 4 threads per edge row in phase 1. Deterministic tree reductions only.

typedef unsigned short ushort_t;
typedef __attribute__((ext_vector_type(8))) short short8;
typedef __attribute__((ext_vector_type(4))) float f32x4;

__device__ __forceinline__ ushort_t f2bf(float f) {
  unsigned int x = __builtin_bit_cast(unsigned int, f);
  x += 0x7fffu + ((x >> 16) & 1u);
  return (ushort_t)(x >> 16);
}

__global__ void k_sent777(float* out0) { out0[threadIdx.x] = 777.f; }

// ---------------- kernel 1: per-node pre-projections ----------------
__global__ __launch_bounds__(128)
void k_pre(const float* nf, const float* We1, const float* be1,
           const float* Wa, float* pre_i, float* pre_j, float* api, float* apj) {
  int r = blockIdx.x, t = threadIdx.x;
  __shared__ float nfv[128];
  __shared__ float red[4];
  nfv[t] = nf[(size_t)r * 128 + t];
  __syncthreads();
  float s1 = be1[t], s2 = 0.f;
  for (int c = 0; c < 128; ++c) {
    float x = nfv[c];
    s1 += x * We1[c * 128 + t];
    s2 += x * We1[(128 + c) * 128 + t];
  }
  pre_i[(size_t)r * 128 + t] = s1;
  pre_j[(size_t)r * 128 + t] = s2;
  float t1 = nfv[t] * Wa[t];
  float t2 = nfv[t] * Wa[128 + t];
#pragma unroll
  for (int o = 32; o > 0; o >>= 1) { t1 += __shfl_down(t1, o); t2 += __shfl_down(t2, o); }
  if ((t & 63) == 0) { red[(t >> 6) * 2] = t1; red[(t >> 6) * 2 + 1] = t2; }
  __syncthreads();
  if (t == 0) { api[r] = red[0] + red[2]; apj[r] = red[1] + red[3]; }
}

// ---------------- kernel 2: pack We2 (fp32) into bf16 MFMA A^T-fragments ----
// bpack[((ks*8+mt)*64 + l)*8 + e] = bf16(We2[ks*32 + (l>>4)*8 + e][mt*16 + (l&15)])
// As A-operand of the swapped GEMM this is A[m][k] = We2^T[m][k].
__global__ __launch_bounds__(256)
void k_pack(const float* We2, ushort_t* bpack) {
  int t = blockIdx.x * 256 + threadIdx.x;
  if (t >= 2048) return;
  int ks = t >> 9, mt = (t >> 6) & 7, l = t & 63;
  int kb = ks * 32 + (l >> 4) * 8, col = mt * 16 + (l & 15);
#pragma unroll
  for (int e = 0; e < 8; ++e) bpack[t * 8 + e] = f2bf(We2[(kb + e) * 128 + col]);
}

// ---------------- kernel 3: edge MLP + attention + reductions ----------------
// grid 2048: block = (r = b*256+i, half of j). 512 threads = 8 waves.
// Phase 1: thread t handles row jr = t&127, channels (t>>7)*32..+31.
// Phase 2: wave w owns edge rows [w*16, w*16+16); lane holds row w*16+(lane&15),
//          4 consecutive out-channels per acc fragment (EM^T orientation).
__global__ __launch_bounds__(512, 4)
void k_edge(const float* co, const float* efo, const float* mk,
            const float* We1, const float* be2, const float* Wa, const float* ba,
            const float* lnes, const float* lneb, const int* eidx,
            const float* pre_i, const float* pre_j, const float* api, const float* apj,
            const ushort_t* bpack, float* oute, float* nm2, float* cd2) {
  __shared__ __align__(16) ushort_t h1s[128 * 136];  // bf16 tile, 136-elem row stride
  __shared__ float wef[17 * 128];   // We1 rows 257..272 (ef) then row 256 (d2)
  __shared__ float lns[128], lnb[128];
  __shared__ float attw[128];
  __shared__ float lnS[512], lnSS[512];
  __shared__ float nmp[8][128];
  __shared__ float cred[2][3];

  const int bx = blockIdx.x;
  const int r = bx >> 1, half = bx & 1;
  const int b = r >> 8;
  const int t = threadIdx.x;          // 0..511
  const int lane = t & 63, w = t >> 6;

  for (int q = t; q < 17 * 128; q += 512) {
    int e = q >> 7, c = q & 127;
    int row = (e < 16) ? (257 + e) : 256;
    wef[q] = We1[row * 128 + c];
  }
  if (t < 128) { lns[t] = lnes[t]; }
  else if (t < 256) { lnb[t - 128] = lneb[t - 128]; }
  __syncthreads();

  // ---- phase 1 ----
  const int jr = t & 127, ch = t >> 7;  // row in tile, channel quarter (0..3)
  const int j = half * 128 + jr;
  const int gj = b * 256 + j;

  float dx = co[r * 3 + 0] - co[gj * 3 + 0];
  float dy = co[r * 3 + 1] - co[gj * 3 + 1];
  float dz = co[r * 3 + 2] - co[gj * 3 + 2];
  float d2 = dx * dx + dy * dy + dz * dz;

  float efv[17];
  {
    const float* efp = efo + ((size_t)r * 256 + j) * 16;
    f32x4 e0 = *reinterpret_cast<const f32x4*>(efp);
    f32x4 e1 = *reinterpret_cast<const f32x4*>(efp + 4);
    f32x4 e2 = *reinterpret_cast<const f32x4*>(efp + 8);
    f32x4 e3 = *reinterpret_cast<const f32x4*>(efp + 12);
#pragma unroll
    for (int x = 0; x < 4; ++x) {
      efv[x] = e0[x]; efv[4 + x] = e1[x]; efv[8 + x] = e2[x]; efv[12 + x] = e3[x];
    }
  }
  efv[16] = d2;

  if (ch == 0) {  // waves 0,1: attention + coord-dir for own row
    float a = api[r] + apj[gj] + ba[0] + d2 * Wa[256];
#pragma unroll
    for (int e = 0; e < 16; ++e) a += efv[e] * Wa[257 + e];
    float att = 1.f / (1.f + __expf(-a));
    float aw = att * (float)eidx[(size_t)r * 256 + j];
    attw[jr] = aw * mk[r] * mk[gj];
    float invn = rsqrtf(d2 + 1e-8f);
    float c0 = dx * invn * aw, c1 = dy * invn * aw, c2 = dz * invn * aw;
#pragma unroll
    for (int o = 32; o > 0; o >>= 1) {
      c0 += __shfl_down(c0, o); c1 += __shfl_down(c1, o); c2 += __shfl_down(c2, o);
    }
    if (lane == 0) { cred[w][0] = c0; cred[w][1] = c1; cred[w][2] = c2; }
  }

  // h1 quarter-row (32 channels): fp32 regs, partial LN stats
  const int cbase = ch * 32;
  const f32x4* pi4 = reinterpret_cast<const f32x4*>(pre_i + (size_t)r * 128 + cbase);
  const f32x4* pj4 = reinterpret_cast<const f32x4*>(pre_j + (size_t)gj * 128 + cbase);
  const f32x4* wef4 = reinterpret_cast<const f32x4*>(wef);
  float h[32];
  float s = 0.f, ss = 0.f;
#pragma unroll
  for (int c4 = 0; c4 < 8; ++c4) {
    f32x4 v = pi4[c4] + pj4[c4];
#pragma unroll
    for (int e = 0; e < 17; ++e) v += efv[e] * wef4[e * 32 + (cbase >> 2) + c4];
#pragma unroll
    for (int x = 0; x < 4; ++x) { h[c4 * 4 + x] = v[x]; s += v[x]; ss += v[x] * v[x]; }
  }
  lnS[t] = s; lnSS[t] = ss;
  __syncthreads();
  // all 4 owners of a row compute identical sums (same order -> bit-identical)
  float st  = lnS[jr] + lnS[jr + 128] + lnS[jr + 256] + lnS[jr + 384];
  float sst = lnSS[jr] + lnSS[jr + 128] + lnSS[jr + 256] + lnSS[jr + 384];
  float mean = st * (1.f / 128.f);
  float var = fmaxf(sst * (1.f / 128.f) - mean * mean, 0.f);
  float rsv = rsqrtf(var + 1e-6f);
  ushort_t* hrow = h1s + jr * 136 + cbase;
#pragma unroll
  for (int q8 = 0; q8 < 4; ++q8) {
    short8 pk;
#pragma unroll
    for (int x = 0; x < 8; ++x) {
      int c = q8 * 8 + x;
      float gv = (h[c] - mean) * rsv * lns[cbase + c] + lnb[cbase + c];
      pk[x] = (short)f2bf(fmaxf(gv, 0.f));
    }
    *reinterpret_cast<short8*>(hrow + q8 * 8) = pk;
  }
  __syncthreads();

  if (t == 0) {
#pragma unroll
    for (int d = 0; d < 3; ++d)
      cd2[(size_t)(half * 1024 + r) * 3 + d] = cred[0][d] + cred[1][d];
  }

  // ---- phase 2: EM^T tiles = We2^T (A) x H1^T (B); coalesced f32x4 stores ----
  f32x4 acc[8];
#pragma unroll
  for (int mt = 0; mt < 8; ++mt) acc[mt] = (f32x4){0.f, 0.f, 0.f, 0.f};

  const short* h1p = reinterpret_cast<const short*>(h1s);
  const int nrow = w * 16 + (lane & 15);      // tile edge-row this lane covers
#pragma unroll
  for (int ks = 0; ks < 4; ++ks) {
    short8 hfr = *reinterpret_cast<const short8*>(
        h1p + nrow * 136 + ks * 32 + ((lane >> 4) * 8));
#pragma unroll
    for (int mt = 0; mt < 8; ++mt) {
      short8 afr = *reinterpret_cast<const short8*>(bpack + (((ks * 8 + mt) * 64 + lane) * 8));
      acc[mt] = __builtin_amdgcn_mfma_f32_16x16x32_bf16(afr, hfr, acc[mt], 0, 0, 0);
    }
  }

  const size_t obase = ((size_t)r * 256 + half * 128) * 128;
  const float wgt = attw[nrow];
  const int mq = (lane >> 4) * 4;             // 4-channel quad within m-tile
  float pm[8][4];
#pragma unroll
  for (int mt = 0; mt < 8; ++mt) {
    f32x4 b4 = *reinterpret_cast<const f32x4*>(be2 + mt * 16 + mq);
    f32x4 val = acc[mt] + b4;
    *reinterpret_cast<f32x4*>(oute + obase + (size_t)nrow * 128 + mt * 16 + mq) = val;
#pragma unroll
    for (int x = 0; x < 4; ++x) pm[mt][x] = val[x] * wgt;
  }
  // reduce over the 16 lanes (rows) sharing each m-quad
#pragma unroll
  for (int mt = 0; mt < 8; ++mt)
#pragma unroll
    for (int x = 0; x < 4; ++x) {
      float v = pm[mt][x];
      v += __shfl_xor(v, 1); v += __shfl_xor(v, 2);
      v += __shfl_xor(v, 4); v += __shfl_xor(v, 8);
      pm[mt][x] = v;
    }
  if ((lane & 15) == 0) {
#pragma unroll
    for (int mt = 0; mt < 8; ++mt)
#pragma unroll
      for (int x = 0; x < 4; ++x) nmp[w][mt * 16 + mq + x] = pm[mt][x];
  }
  __syncthreads();
  if (t < 128) {
    float acc8 = nmp[0][t] + nmp[1][t] + nmp[2][t] + nmp[3][t]
               + nmp[4][t] + nmp[5][t] + nmp[6][t] + nmp[7][t];
    nm2[(size_t)(half * 1024 + r) * 128 + t] = acc8;
  }
}

// ---------------- kernel 4: node MLP + coord MLP + outputs ----------------
__device__ __forceinline__ float bsum128(float v, float* red, int t) {
#pragma unroll
  for (int o = 32; o > 0; o >>= 1) v += __shfl_down(v, o);
  __syncthreads();
  if ((t & 63) == 0) red[t >> 6] = v;
  __syncthreads();
  return red[0] + red[1];
}

__global__ __launch_bounds__(128)
void k_node(const float* nf, const float* co, const float* mk,
            const float* Wn1, const float* bn1, const float* lnns, const float* lnnb,
            const float* Wn2, const float* bn2,
            const float* Wc1, const float* bc1, const float* lncs, const float* lncb,
            const float* Wc2, const float* bc2,
            const float* nm2, const float* cd2,
            float* out0, float* out1) {
  int r = blockIdx.x, t = threadIdx.x;
  __shared__ float nin[256];
  __shared__ float hf[128];
  __shared__ float red[2];
  float nfv = nf[(size_t)r * 128 + t];
  float nmv = nm2[(size_t)r * 128 + t] + nm2[(size_t)(1024 + r) * 128 + t];
  nin[t] = nfv; nin[128 + t] = nmv;
  __syncthreads();
  float s1 = bn1[t];
  for (int c = 0; c < 256; ++c) s1 += nin[c] * Wn1[c * 128 + t];
  float mean = bsum128(s1, red, t) * (1.f / 128.f);
  float var = fmaxf(bsum128(s1 * s1, red, t) * (1.f / 128.f) - mean * mean, 0.f);
  float hv = (s1 - mean) * rsqrtf(var + 1e-6f) * lnns[t] + lnnb[t];
  hv = fmaxf(hv, 0.f);
  hf[t] = hv;
  __syncthreads();
  float o1 = bn2[t] + nfv;  // residual
  for (int c = 0; c < 128; ++c) o1 += hf[c] * Wn2[c * 128 + t];
  out0[(size_t)r * 128 + t] = o1;
  // coord MLP on node_messages
  float g = bc1[t];
  for (int c = 0; c < 128; ++c) g += nin[128 + c] * Wc1[c * 128 + t];
  float gm = bsum128(g, red, t) * (1.f / 128.f);
  float gv = fmaxf(bsum128(g * g, red, t) * (1.f / 128.f) - gm * gm, 0.f);
  float gh = fmaxf((g - gm) * rsqrtf(gv + 1e-6f) * lncs[t] + lncb[t], 0.f);
  float cm = bsum128(gh * Wc2[t], red, t) + bc2[0];
  if (t < 3) {
    float cd = cd2[(size_t)r * 3 + t] + cd2[(size_t)(1024 + r) * 3 + t];
    float nc = co[(size_t)r * 3 + t] + cd * cm * mk[r];
    out1[(size_t)r * 3 + t] = nc;
  }
}

extern "C" void kernel_launch(void* const* d_in, const int* in_sizes, int n_in,
                              void* d_out, int out_size, void* d_ws, size_t ws_size,
                              hipStream_t stream) {
  const float* nf   = (const float*)d_in[0];
  const float* co   = (const float*)d_in[1];
  const float* efo  = (const float*)d_in[2];
  const float* mk   = (const float*)d_in[3];
  const float* We1  = (const float*)d_in[4];
  const float* be1  = (const float*)d_in[5];
  const float* lnes = (const float*)d_in[6];
  const float* lneb = (const float*)d_in[7];
  const float* We2  = (const float*)d_in[8];
  const float* be2  = (const float*)d_in[9];
  const float* Wa   = (const float*)d_in[10];
  const float* ba   = (const float*)d_in[11];
  const float* Wn1  = (const float*)d_in[12];
  const float* bn1  = (const float*)d_in[13];
  const float* lnns = (const float*)d_in[14];
  const float* lnnb = (const float*)d_in[15];
  const float* Wn2  = (const float*)d_in[16];
  const float* bn2  = (const float*)d_in[17];
  const float* Wc1  = (const float*)d_in[18];
  const float* bc1  = (const float*)d_in[19];
  const float* lncs = (const float*)d_in[20];
  const float* lncb = (const float*)d_in[21];
  const float* Wc2  = (const float*)d_in[22];
  const float* bc2  = (const float*)d_in[23];
  const int* eidx   = (const int*)d_in[24];

  float* out0 = (float*)d_out;        // new_node_features [4,256,128]
  float* out1 = out0 + 131072;        // new_coordinates  [4,256,3]
  float* oute = out1 + 3072;          // new_edge_features [4,256,256,128]

  const size_t need = (size_t)(131072 + 131072 + 1024 + 1024 + 262144 + 6144) * 4 + 16384 * 2;
  if (ws_size < need) {  // diagnostic sentinel: absmax ~777 => ws too small
    k_sent777<<<1, 128, 0, stream>>>(out0);
    return;
  }
  float* ws    = (float*)d_ws;
  float* pre_i = ws;
  float* pre_j = pre_i + 131072;
  float* api   = pre_j + 131072;
  float* apj   = api + 1024;
  float* nm2   = apj + 1024;
  float* cd2   = nm2 + 262144;
  ushort_t* bpack = (ushort_t*)(cd2 + 6144);

  k_pre<<<1024, 128, 0, stream>>>(nf, We1, be1, Wa, pre_i, pre_j, api, apj);
  k_pack<<<8, 256, 0, stream>>>(We2, bpack);
  k_edge<<<2048, 512, 0, stream>>>(co, efo, mk, We1, be2, Wa, ba, lnes, lneb, eidx,
                                   pre_i, pre_j, api, apj, bpack, oute, nm2, cd2);
  k_node<<<1024, 128, 0, stream>>>(nf, co, mk, Wn1, bn1, lnns, lnnb, Wn2, bn2,
                                   Wc1, bc1, lncs, lncb, Wc2, bc2, nm2, cd2, out0, out1);
}

// Round 6
// 101.109 us; speedup vs baseline: 1.1301x; 1.1301x over previous
//
#include <hip/hip_runtime.h>
#include <hip/hip_bf16.h>

// EGNN layer, MI355X. B=4, N=256, H=128, E=16, EIN=273. All I/O float32.
// h1 = pre_i(i) + pre_j(j) + [ef|d2|pad]@Wx via ONE MFMA K-step (K=32) --
// replaces the 544-FMA/136-LDS-broadcast-read per-thread VALU path that was
// LDS-issue-bound (rounds 3-5 invariant). Layer-2 128x128 GEMM via swapped
// mfma (D = We2^T x H1^T) for coalesced dwordx4 stores. 512 thr / 8 waves.
// Deterministic fixed-order reductions only.

typedef unsigned short ushort_t;
typedef __attribute__((ext_vector_type(8))) short short8;
typedef __attribute__((ext_vector_type(4))) float f32x4;

__device__ __forceinline__ ushort_t f2bf(float f) {
  unsigned int x = __builtin_bit_cast(unsigned int, f);
  x += 0x7fffu + ((x >> 16) & 1u);
  return (ushort_t)(x >> 16);
}
__device__ __forceinline__ float bf2f(ushort_t u) {
  unsigned int x = ((unsigned int)u) << 16;
  return __builtin_bit_cast(float, x);
}

__global__ void k_sent777(float* out0) { out0[threadIdx.x] = 777.f; }

// ---------------- kernel 1: per-node pre-projections ----------------
__global__ __launch_bounds__(128)
void k_pre(const float* nf, const float* We1, const float* be1,
           const float* Wa, float* pre_i, float* pre_j, float* api, float* apj) {
  int r = blockIdx.x, t = threadIdx.x;
  __shared__ float nfv[128];
  __shared__ float red[4];
  nfv[t] = nf[(size_t)r * 128 + t];
  __syncthreads();
  float s1 = be1[t], s2 = 0.f;
  for (int c = 0; c < 128; ++c) {
    float x = nfv[c];
    s1 += x * We1[c * 128 + t];
    s2 += x * We1[(128 + c) * 128 + t];
  }
  pre_i[(size_t)r * 128 + t] = s1;
  pre_j[(size_t)r * 128 + t] = s2;
  float t1 = nfv[t] * Wa[t];
  float t2 = nfv[t] * Wa[128 + t];
#pragma unroll
  for (int o = 32; o > 0; o >>= 1) { t1 += __shfl_down(t1, o); t2 += __shfl_down(t2, o); }
  if ((t & 63) == 0) { red[(t >> 6) * 2] = t1; red[(t >> 6) * 2 + 1] = t2; }
  __syncthreads();
  if (t == 0) { api[r] = red[0] + red[2]; apj[r] = red[1] + red[3]; }
}

// ---------------- kernel 2: pack We2 (fp32) into bf16 MFMA A^T-fragments ----
__global__ __launch_bounds__(256)
void k_pack(const float* We2, ushort_t* bpack) {
  int t = blockIdx.x * 256 + threadIdx.x;
  if (t >= 2048) return;
  int ks = t >> 9, mt = (t >> 6) & 7, l = t & 63;
  int kb = ks * 32 + (l >> 4) * 8, col = mt * 16 + (l & 15);
#pragma unroll
  for (int e = 0; e < 8; ++e) bpack[t * 8 + e] = f2bf(We2[(kb + e) * 128 + col]);
}

// ---------------- kernel 3: edge MLP + attention + reductions ----------------
// grid 2048: block = (r = b*256+i, half of j). 512 threads = 8 waves.
// Phase 1 (MFMA): D1[128 rows x 128 chan]; wave w owns chan-stripe w*16..+16.
// Phase 2: as round 5 (EM^T = We2^T x H1^T), coalesced f32x4 stores.
__global__ __launch_bounds__(512, 2)
void k_edge(const float* co, const float* efo, const float* mk,
            const float* We1, const float* be2, const float* Wa, const float* ba,
            const float* lnes, const float* lneb, const int* eidx,
            const float* pre_i, const float* pre_j, const float* api, const float* apj,
            const ushort_t* bpack, float* oute, float* nm2, float* cd2) {
  __shared__ __align__(16) ushort_t A_lds[8 * 64 * 8];   // 8KB, frag-order [mt][lane][e]
  __shared__ __align__(16) ushort_t h1s[128 * 136];      // 34.8KB bf16 h1 tile
  __shared__ float2 mrsv[128];                           // per-row {mean, rsv}
  __shared__ float attw[128];
  __shared__ float nmp[8][128];
  __shared__ float cred[2][3];

  const int bx = blockIdx.x;
  const int r = bx >> 1, half = bx & 1;
  const int b = r >> 8;
  const int t = threadIdx.x;          // 0..511
  const int lane = t & 63, w = t >> 6;
  const int s4 = lane >> 4;           // 0..3 (k-slice / row-quad selector)
  const int chan = w * 16 + (lane & 15);
  const int gbase = b * 256 + half * 128;

  // ---- per-lane W fragment (K=32: rows 0..15=Wef, 16=wd2, 17..31=0) ----
  short8 wfrag;
#pragma unroll
  for (int e = 0; e < 8; ++e) {
    int k = s4 * 8 + e;
    float wv = 0.f;
    if (k < 16) wv = We1[(257 + k) * 128 + chan];
    else if (k == 16) wv = We1[256 * 128 + chan];
    wfrag[e] = (short)f2bf(wv);
  }
  const float preIc = pre_i[(size_t)r * 128 + chan];
  const float lnsc = lnes[chan], lnbc = lneb[chan];

  // ---- A-tile staging (frag order): thread t -> (mt=t>>6, l=t&63) ----
  {
    const int mt = t >> 6, l = t & 63, sl = l >> 4, row = mt * 16 + (l & 15);
    short8* dst = reinterpret_cast<short8*>(A_lds + ((size_t)(mt * 64 + l)) * 8);
    if (sl < 2) {
      const float* efp = efo + ((size_t)(r * 256 + half * 128 + row)) * 16 + sl * 8;
      f32x4 e0 = *reinterpret_cast<const f32x4*>(efp);
      f32x4 e1 = *reinterpret_cast<const f32x4*>(efp + 4);
      short8 pk;
#pragma unroll
      for (int x = 0; x < 4; ++x) { pk[x] = (short)f2bf(e0[x]); pk[4 + x] = (short)f2bf(e1[x]); }
      *dst = pk;
    } else if (sl == 3) {
      *dst = (short8){0, 0, 0, 0, 0, 0, 0, 0};
    }
    // sl==2 written by attention pass (d2)
  }

  // ---- attention + d2 + coord-dir (threads 0..127, one per edge row) ----
  if (t < 128) {
    const int j = half * 128 + t;
    const int gj = b * 256 + j;
    float dx = co[r * 3 + 0] - co[gj * 3 + 0];
    float dy = co[r * 3 + 1] - co[gj * 3 + 1];
    float dz = co[r * 3 + 2] - co[gj * 3 + 2];
    float d2 = dx * dx + dy * dy + dz * dz;

    float a = api[r] + apj[gj] + ba[0] + d2 * Wa[256];
    const float* efp = efo + ((size_t)r * 256 + j) * 16;
    f32x4 e0 = *reinterpret_cast<const f32x4*>(efp);
    f32x4 e1 = *reinterpret_cast<const f32x4*>(efp + 4);
    f32x4 e2 = *reinterpret_cast<const f32x4*>(efp + 8);
    f32x4 e3 = *reinterpret_cast<const f32x4*>(efp + 12);
#pragma unroll
    for (int x = 0; x < 4; ++x) {
      a += e0[x] * Wa[257 + x] + e1[x] * Wa[261 + x]
         + e2[x] * Wa[265 + x] + e3[x] * Wa[269 + x];
    }
    float att = 1.f / (1.f + __expf(-a));
    float aw = att * (float)eidx[(size_t)r * 256 + j];
    attw[t] = aw * mk[r] * mk[gj];

    // d2 into A-tile: (mt=t>>4, l = 32 + (t&15)), elems [d2,0,...,0]
    short8 dz8 = (short8){0, 0, 0, 0, 0, 0, 0, 0};
    dz8[0] = (short)f2bf(d2);
    *reinterpret_cast<short8*>(A_lds + ((size_t)((t >> 4) * 64 + 32 + (t & 15))) * 8) = dz8;

    float invn = rsqrtf(d2 + 1e-8f);
    float c0 = dx * invn * aw, c1 = dy * invn * aw, c2 = dz * invn * aw;
#pragma unroll
    for (int o = 32; o > 0; o >>= 1) {
      c0 += __shfl_down(c0, o); c1 += __shfl_down(c1, o); c2 += __shfl_down(c2, o);
    }
    if (lane == 0) { cred[w][0] = c0; cred[w][1] = c1; cred[w][2] = c2; }
  }
  __syncthreads();

  // ---- phase 1 MFMA: D1[mt] = A_frag[mt] x wfrag; add pre terms; raw h1 -> LDS
  f32x4 acc1[8];
#pragma unroll
  for (int mt = 0; mt < 8; ++mt) {
    short8 afr = *reinterpret_cast<const short8*>(A_lds + ((size_t)(mt * 64 + lane)) * 8);
    acc1[mt] = __builtin_amdgcn_mfma_f32_16x16x32_bf16(
        afr, wfrag, (f32x4){0.f, 0.f, 0.f, 0.f}, 0, 0, 0);
  }
#pragma unroll
  for (int mt = 0; mt < 8; ++mt) {
#pragma unroll
    for (int reg = 0; reg < 4; ++reg) {
      int row = mt * 16 + s4 * 4 + reg;
      float v = acc1[mt][reg] + preIc + pre_j[((size_t)(gbase + row)) * 128 + chan];
      acc1[mt][reg] = v;                       // keep fp32 value for LN apply
      h1s[row * 136 + chan] = f2bf(v);         // raw h1 (bf16) for row stats
    }
  }
  __syncthreads();

  // ---- row LN stats (one owner thread per row, fixed-order serial sum) ----
  if (t < 128) {
    const short8* hr8 = reinterpret_cast<const short8*>(h1s + t * 136);
    float sum = 0.f, ss = 0.f;
#pragma unroll
    for (int q = 0; q < 16; ++q) {
      short8 pk = hr8[q];
#pragma unroll
      for (int x = 0; x < 8; ++x) {
        float f = bf2f((ushort_t)pk[x]);
        sum += f; ss += f * f;
      }
    }
    float mean = sum * (1.f / 128.f);
    float var = fmaxf(ss * (1.f / 128.f) - mean * mean, 0.f);
    mrsv[t] = make_float2(mean, rsqrtf(var + 1e-6f));
  }
  __syncthreads();

  // ---- apply LN + ReLU, write final h1 (bf16) ----
#pragma unroll
  for (int mt = 0; mt < 8; ++mt) {
#pragma unroll
    for (int reg = 0; reg < 4; ++reg) {
      int row = mt * 16 + s4 * 4 + reg;
      float2 mr = mrsv[row];
      float gv = (acc1[mt][reg] - mr.x) * mr.y * lnsc + lnbc;
      h1s[row * 136 + chan] = f2bf(fmaxf(gv, 0.f));
    }
  }
  __syncthreads();

  if (t == 0) {
#pragma unroll
    for (int d = 0; d < 3; ++d)
      cd2[(size_t)(half * 1024 + r) * 3 + d] = cred[0][d] + cred[1][d];
  }

  // ---- phase 2: EM^T tiles = We2^T (A) x H1^T (B); coalesced f32x4 stores ----
  f32x4 acc[8];
#pragma unroll
  for (int mt = 0; mt < 8; ++mt) acc[mt] = (f32x4){0.f, 0.f, 0.f, 0.f};

  const short* h1p = reinterpret_cast<const short*>(h1s);
  const int nrow = w * 16 + (lane & 15);      // tile edge-row this lane covers
#pragma unroll
  for (int ks = 0; ks < 4; ++ks) {
    short8 hfr = *reinterpret_cast<const short8*>(
        h1p + nrow * 136 + ks * 32 + (s4 * 8));
#pragma unroll
    for (int mt = 0; mt < 8; ++mt) {
      short8 afr = *reinterpret_cast<const short8*>(bpack + (((ks * 8 + mt) * 64 + lane) * 8));
      acc[mt] = __builtin_amdgcn_mfma_f32_16x16x32_bf16(afr, hfr, acc[mt], 0, 0, 0);
    }
  }

  const size_t obase = ((size_t)r * 256 + half * 128) * 128;
  const float wgt = attw[nrow];
  const int mq = s4 * 4;                      // 4-channel quad within m-tile
  float pm[8][4];
#pragma unroll
  for (int mt = 0; mt < 8; ++mt) {
    f32x4 b4 = *reinterpret_cast<const f32x4*>(be2 + mt * 16 + mq);
    f32x4 val = acc[mt] + b4;
    *reinterpret_cast<f32x4*>(oute + obase + (size_t)nrow * 128 + mt * 16 + mq) = val;
#pragma unroll
    for (int x = 0; x < 4; ++x) pm[mt][x] = val[x] * wgt;
  }
#pragma unroll
  for (int mt = 0; mt < 8; ++mt)
#pragma unroll
    for (int x = 0; x < 4; ++x) {
      float v = pm[mt][x];
      v += __shfl_xor(v, 1); v += __shfl_xor(v, 2);
      v += __shfl_xor(v, 4); v += __shfl_xor(v, 8);
      pm[mt][x] = v;
    }
  if ((lane & 15) == 0) {
#pragma unroll
    for (int mt = 0; mt < 8; ++mt)
#pragma unroll
      for (int x = 0; x < 4; ++x) nmp[w][mt * 16 + mq + x] = pm[mt][x];
  }
  __syncthreads();
  if (t < 128) {
    float acc8 = nmp[0][t] + nmp[1][t] + nmp[2][t] + nmp[3][t]
               + nmp[4][t] + nmp[5][t] + nmp[6][t] + nmp[7][t];
    nm2[(size_t)(half * 1024 + r) * 128 + t] = acc8;
  }
}

// ---------------- kernel 4: node MLP + coord MLP + outputs ----------------
__device__ __forceinline__ float bsum128(float v, float* red, int t) {
#pragma unroll
  for (int o = 32; o > 0; o >>= 1) v += __shfl_down(v, o);
  __syncthreads();
  if ((t & 63) == 0) red[t >> 6] = v;
  __syncthreads();
  return red[0] + red[1];
}

__global__ __launch_bounds__(128)
void k_node(const float* nf, const float* co, const float* mk,
            const float* Wn1, const float* bn1, const float* lnns, const float* lnnb,
            const float* Wn2, const float* bn2,
            const float* Wc1, const float* bc1, const float* lncs, const float* lncb,
            const float* Wc2, const float* bc2,
            const float* nm2, const float* cd2,
            float* out0, float* out1) {
  int r = blockIdx.x, t = threadIdx.x;
  __shared__ float nin[256];
  __shared__ float hf[128];
  __shared__ float red[2];
  float nfv = nf[(size_t)r * 128 + t];
  float nmv = nm2[(size_t)r * 128 + t] + nm2[(size_t)(1024 + r) * 128 + t];
  nin[t] = nfv; nin[128 + t] = nmv;
  __syncthreads();
  float s1 = bn1[t];
  for (int c = 0; c < 256; ++c) s1 += nin[c] * Wn1[c * 128 + t];
  float mean = bsum128(s1, red, t) * (1.f / 128.f);
  float var = fmaxf(bsum128(s1 * s1, red, t) * (1.f / 128.f) - mean * mean, 0.f);
  float hv = (s1 - mean) * rsqrtf(var + 1e-6f) * lnns[t] + lnnb[t];
  hv = fmaxf(hv, 0.f);
  hf[t] = hv;
  __syncthreads();
  float o1 = bn2[t] + nfv;  // residual
  for (int c = 0; c < 128; ++c) o1 += hf[c] * Wn2[c * 128 + t];
  out0[(size_t)r * 128 + t] = o1;
  // coord MLP on node_messages
  float g = bc1[t];
  for (int c = 0; c < 128; ++c) g += nin[128 + c] * Wc1[c * 128 + t];
  float gm = bsum128(g, red, t) * (1.f / 128.f);
  float gv = fmaxf(bsum128(g * g, red, t) * (1.f / 128.f) - gm * gm, 0.f);
  float gh = fmaxf((g - gm) * rsqrtf(gv + 1e-6f) * lncs[t] + lncb[t], 0.f);
  float cm = bsum128(gh * Wc2[t], red, t) + bc2[0];
  if (t < 3) {
    float cd = cd2[(size_t)r * 3 + t] + cd2[(size_t)(1024 + r) * 3 + t];
    float nc = co[(size_t)r * 3 + t] + cd * cm * mk[r];
    out1[(size_t)r * 3 + t] = nc;
  }
}

extern "C" void kernel_launch(void* const* d_in, const int* in_sizes, int n_in,
                              void* d_out, int out_size, void* d_ws, size_t ws_size,
                              hipStream_t stream) {
  const float* nf   = (const float*)d_in[0];
  const float* co   = (const float*)d_in[1];
  const float* efo  = (const float*)d_in[2];
  const float* mk   = (const float*)d_in[3];
  const float* We1  = (const float*)d_in[4];
  const float* be1  = (const float*)d_in[5];
  const float* lnes = (const float*)d_in[6];
  const float* lneb = (const float*)d_in[7];
  const float* We2  = (const float*)d_in[8];
  const float* be2  = (const float*)d_in[9];
  const float* Wa   = (const float*)d_in[10];
  const float* ba   = (const float*)d_in[11];
  const float* Wn1  = (const float*)d_in[12];
  const float* bn1  = (const float*)d_in[13];
  const float* lnns = (const float*)d_in[14];
  const float* lnnb = (const float*)d_in[15];
  const float* Wn2  = (const float*)d_in[16];
  const float* bn2  = (const float*)d_in[17];
  const float* Wc1  = (const float*)d_in[18];
  const float* bc1  = (const float*)d_in[19];
  const float* lncs = (const float*)d_in[20];
  const float* lncb = (const float*)d_in[21];
  const float* Wc2  = (const float*)d_in[22];
  const float* bc2  = (const float*)d_in[23];
  const int* eidx   = (const int*)d_in[24];

  float* out0 = (float*)d_out;        // new_node_features [4,256,128]
  float* out1 = out0 + 131072;        // new_coordinates  [4,256,3]
  float* oute = out1 + 3072;          // new_edge_features [4,256,256,128]

  const size_t need = (size_t)(131072 + 131072 + 1024 + 1024 + 262144 + 6144) * 4 + 16384 * 2;
  if (ws_size < need) {  // diagnostic sentinel: absmax ~777 => ws too small
    k_sent777<<<1, 128, 0, stream>>>(out0);
    return;
  }
  float* ws    = (float*)d_ws;
  float* pre_i = ws;
  float* pre_j = pre_i + 131072;
  float* api   = pre_j + 131072;
  float* apj   = api + 1024;
  float* nm2   = apj + 1024;
  float* cd2   = nm2 + 262144;
  ushort_t* bpack = (ushort_t*)(cd2 + 6144);

  k_pre<<<1024, 128, 0, stream>>>(nf, We1, be1, Wa, pre_i, pre_j, api, apj);
  k_pack<<<8, 256, 0, stream>>>(We2, bpack);
  k_edge<<<2048, 512, 0, stream>>>(co, efo, mk, We1, be2, Wa, ba, lnes, lneb, eidx,
                                   pre_i, pre_j, api, apj, bpack, oute, nm2, cd2);
  k_node<<<1024, 128, 0, stream>>>(nf, co, mk, Wn1, bn1, lnns, lnnb, Wn2, bn2,
                                   Wc1, bc1, lncs, lncb, Wc2, bc2, nm2, cd2, out0, out1);
}